// Round 7
// baseline (510.719 us; speedup 1.0000x reference)
//
#include <hip/hip_runtime.h>

#define IMG     512
#define VALID   506          // IMG - 6
#define NPLANES 96           // 32 * 3
#define R       13           // output rows per wave-band
#define NBANDS  39           // 39*13 = 507 >= 506

struct Q { float4 x0, x1, y0, y1; };

__device__ __forceinline__ float shfl_next(float v, int baddr) {
    return __int_as_float(__builtin_amdgcn_ds_bpermute(baddr, __float_as_int(v)));
}
__device__ __forceinline__ float comp4(const float4 v, int k) {   // k literal -> folds
    return k == 0 ? v.x : k == 1 ? v.y : k == 2 ? v.z : v.w;
}
__device__ __forceinline__ float comp8(const float4 a, const float4 b, int k) {
    return k < 4 ? comp4(a, k) : comp4(b, k - 4);
}

__device__ __forceinline__ void addv(float4& V, const float4 p) {
    V.x += p.x; V.y += p.y; V.z += p.z; V.w += p.w;
}
__device__ __forceinline__ void subv(float4& V, const float4 p) {
    V.x -= p.x; V.y -= p.y; V.z -= p.z; V.w -= p.w;
}
__device__ __forceinline__ void addmul(float4& V, const float4 p, const float4 q) {
    V.x = fmaf(p.x, q.x, V.x); V.y = fmaf(p.y, q.y, V.y);
    V.z = fmaf(p.z, q.z, V.z); V.w = fmaf(p.w, q.w, V.w);
}
__device__ __forceinline__ void submul(float4& V, const float4 p, const float4 q) {
    V.x = fmaf(-p.x, q.x, V.x); V.y = fmaf(-p.y, q.y, V.y);
    V.z = fmaf(-p.z, q.z, V.z); V.w = fmaf(-p.w, q.w, V.w);
}

__global__ __launch_bounds__(128, 4) void ssim_wave_kernel(
    const float* __restrict__ pred,
    const float* __restrict__ target,
    double* __restrict__ accum)
{
    const int t     = threadIdx.x;
    const int lane  = t & 63;
    const int band  = blockIdx.y * 2 + (t >> 6);   // 0..39 (39 = pad band)
    const int plane = blockIdx.x;                  // plane-major: plane p -> XCD p%8
    const int row0  = band * R;
    const int col   = lane << 3;                   // this lane's 8 columns

    if (row0 >= VALID) return;                     // pad band (no barriers used)

    const size_t pbase = (size_t)plane * (IMG * IMG);
    const float* __restrict__ pp = pred   + pbase + col;
    const float* __restrict__ pt = target + pbase + col;

    const int baddr = ((lane + 1) & 63) << 2;      // ds_bpermute addr: lane+1

    float4 z = make_float4(0.f, 0.f, 0.f, 0.f);
    float4 Vx_a = z, Vx_b = z, Vy_a = z, Vy_b = z;
    float4 Vss_a = z, Vss_b = z, Vxy_a = z, Vxy_b = z;   // Vss = Vxx + Vyy merged

#define LOADQ(q, r) do { int _rr = (r) < (IMG - 1) ? (r) : (IMG - 1);             \
    const float4* _p  = reinterpret_cast<const float4*>(pp + (size_t)_rr * IMG); \
    const float4* _q2 = reinterpret_cast<const float4*>(pt + (size_t)_rr * IMG); \
    q.x0 = _p[0]; q.x1 = _p[1]; q.y0 = _q2[0]; q.y1 = _q2[1]; } while (0)

#define ACCQ(q) do {                                                        \
    addv(Vx_a, q.x0); addv(Vx_b, q.x1); addv(Vy_a, q.y0); addv(Vy_b, q.y1); \
    addmul(Vss_a, q.x0, q.x0); addmul(Vss_b, q.x1, q.x1);                   \
    addmul(Vss_a, q.y0, q.y0); addmul(Vss_b, q.y1, q.y1);                   \
    addmul(Vxy_a, q.x0, q.y0); addmul(Vxy_b, q.x1, q.y1); } while (0)

#define SUBQ(q) do {                                                        \
    subv(Vx_a, q.x0); subv(Vx_b, q.x1); subv(Vy_a, q.y0); subv(Vy_b, q.y1); \
    submul(Vss_a, q.x0, q.x0); submul(Vss_b, q.x1, q.x1);                   \
    submul(Vss_a, q.y0, q.y0); submul(Vss_b, q.y1, q.y1);                   \
    submul(Vxy_a, q.x0, q.y0); submul(Vxy_b, q.x1, q.y1); } while (0)

    const float c1 = 0.9604f;   // (0.01*2)^2 * 49^2
    const float c2 = 8.4672f;   // (0.03*2)^2 * 48*49
    float local = 0.f;

#define SSIM_PX(j) do {                                                \
    float t1 = ox * oy;                                                \
    float t2 = fmaf(ox, ox, oy * oy);                                  \
    float n1 = fmaf(2.f, t1, c1);                                      \
    float d1 = t2 + c1;                                                \
    float n2 = fmaf(-2.f, t1, fmaf(98.f, oxy, c2));                    \
    float d2 = fmaf(49.f, oss, c2) - t2;                               \
    float S  = __fdividef(n1 * n2, d1 * d2);                           \
    local += (col + (j) < VALID) ? S : 0.f; } while (0)

    // pixel-major horizontal pass: o-vars slide col->col, shuffles just-in-time
#define HSSIM(i) do { if ((row0 + (i)) < VALID) {                                   \
    float ox  = ((Vx_a.x + Vx_a.y) + (Vx_a.z + Vx_a.w)) + ((Vx_b.x + Vx_b.y) + Vx_b.z); \
    float oy  = ((Vy_a.x + Vy_a.y) + (Vy_a.z + Vy_a.w)) + ((Vy_b.x + Vy_b.y) + Vy_b.z); \
    float oss = ((Vss_a.x + Vss_a.y) + (Vss_a.z + Vss_a.w)) + ((Vss_b.x + Vss_b.y) + Vss_b.z); \
    float oxy = ((Vxy_a.x + Vxy_a.y) + (Vxy_a.z + Vxy_a.w)) + ((Vxy_b.x + Vxy_b.y) + Vxy_b.z); \
    SSIM_PX(0);                                                        \
    ox  += Vx_b.w  - Vx_a.x;  oy  += Vy_b.w  - Vy_a.x;                 \
    oss += Vss_b.w - Vss_a.x; oxy += Vxy_b.w - Vxy_a.x;                \
    SSIM_PX(1);                                                        \
    _Pragma("unroll")                                                  \
    for (int j = 2; j < 8; ++j) {                                      \
        float nx = shfl_next(comp8(Vx_a,  Vx_b,  j - 2), baddr);       \
        float ny = shfl_next(comp8(Vy_a,  Vy_b,  j - 2), baddr);       \
        float ns = shfl_next(comp8(Vss_a, Vss_b, j - 2), baddr);       \
        float nq = shfl_next(comp8(Vxy_a, Vxy_b, j - 2), baddr);       \
        ox  += nx - comp8(Vx_a,  Vx_b,  j - 1);                        \
        oy  += ny - comp8(Vy_a,  Vy_b,  j - 1);                        \
        oss += ns - comp8(Vss_a, Vss_b, j - 1);                        \
        oxy += nq - comp8(Vxy_a, Vxy_b, j - 1);                        \
        SSIM_PX(j);                                                    \
    } } } while (0)

    // ---- slots: NA/NB new-row ping-pong (issue distance 2), OA old-row (distance 1)
    Q NA, NB, OA;

    // ---- software-pipelined prologue: rows r0..r5 accumulated, never <4 loads in flight
    LOADQ(NA, row0 + 0); LOADQ(NB, row0 + 1); LOADQ(OA, row0 + 2);
    ACCQ(NA); LOADQ(NA, row0 + 3);
    ACCQ(NB); LOADQ(NB, row0 + 4);
    ACCQ(OA); LOADQ(OA, row0 + 5);
    ACCQ(NA); LOADQ(NA, row0 + 6);   // iter-0 new row
    ACCQ(NB); LOADQ(NB, row0 + 7);   // iter-1 new row
    ACCQ(OA);

    // ---- main steps: consume -> reissue (counted vmcnt, never drains) -> HSSIM
    // bottom(i) issues OA <- r(i)   (consumed by SUBQ at iter i+1: subtracts r(i))
    //           and   N  <- r(i+8) (consumed by ACCQ at iter i+2)
#define STEP(Nslot, i) do {                                            \
    ACCQ(Nslot);                                                       \
    if ((i) >= 1) SUBQ(OA);                                            \
    if ((i) + 1 < R) LOADQ(OA, row0 + (i));                            \
    if ((i) + 2 < R) LOADQ(Nslot, row0 + (i) + 8);                     \
    HSSIM(i); } while (0)

    STEP(NA, 0);  STEP(NB, 1);  STEP(NA, 2);  STEP(NB, 3);
    STEP(NA, 4);  STEP(NB, 5);  STEP(NA, 6);  STEP(NB, 7);
    STEP(NA, 8);  STEP(NB, 9);  STEP(NA, 10); STEP(NB, 11);
    STEP(NA, 12);

    // per-wave reduce -> one atomic per wave, scattered per plane (no barriers)
    #pragma unroll
    for (int off = 32; off > 0; off >>= 1)
        local += __shfl_down(local, off, 64);
    if (lane == 0)
        atomicAdd(&accum[plane], (double)local);
}

__global__ void ssim_finalize_kernel(const double* __restrict__ accum,
                                     float* __restrict__ out)
{
    const int l = threadIdx.x;           // 64 threads = 1 wave
    double s = accum[l];
    if (l < NPLANES - 64) s += accum[64 + l];
    #pragma unroll
    for (int off = 32; off > 0; off >>= 1)
        s += __shfl_down(s, off, 64);
    if (l == 0) {
        const double n_valid = (double)NPLANES * (double)VALID * (double)VALID;
        out[0] = (float)(1.0 - s / n_valid);
    }
}

extern "C" void kernel_launch(void* const* d_in, const int* in_sizes, int n_in,
                              void* d_out, int out_size, void* d_ws, size_t ws_size,
                              hipStream_t stream) {
    const float* pred   = (const float*)d_in[0];
    const float* target = (const float*)d_in[1];
    float* out = (float*)d_out;
    double* accum = (double*)d_ws;

    hipMemsetAsync(d_ws, 0, NPLANES * sizeof(double), stream);

    // plane-major grid: 96 % 8 == 0 -> all bands of a plane land on one XCD L2.
    // 40 bands x 96 planes = 3744 active waves <= 4096 capacity (1 generation).
    dim3 grid(NPLANES, (NBANDS + 2) / 2);
    ssim_wave_kernel<<<grid, 128, 0, stream>>>(pred, target, accum);
    ssim_finalize_kernel<<<1, 64, 0, stream>>>(accum, out);
}

// Round 8
// 224.553 us; speedup vs baseline: 2.2744x; 2.2744x over previous
//
#include <hip/hip_runtime.h>

#define IMG     512
#define VALID   506          // IMG - 6
#define NPLANES 96           // 32 * 3
#define R       10           // output rows per wave-band
#define NBANDS  51           // 51*10 = 510 >= 506

__device__ __forceinline__ float shfl_next(float v, int baddr) {
    return __int_as_float(__builtin_amdgcn_ds_bpermute(baddr, __float_as_int(v)));
}

__device__ __forceinline__ void addv(float4& V, const float4 p) {
    V.x += p.x; V.y += p.y; V.z += p.z; V.w += p.w;
}
__device__ __forceinline__ void subv(float4& V, const float4 p) {
    V.x -= p.x; V.y -= p.y; V.z -= p.z; V.w -= p.w;
}
__device__ __forceinline__ void addmul(float4& V, const float4 p, const float4 q) {
    V.x = fmaf(p.x, q.x, V.x); V.y = fmaf(p.y, q.y, V.y);
    V.z = fmaf(p.z, q.z, V.z); V.w = fmaf(p.w, q.w, V.w);
}
__device__ __forceinline__ void submul(float4& V, const float4 p, const float4 q) {
    V.x = fmaf(-p.x, q.x, V.x); V.y = fmaf(-p.y, q.y, V.y);
    V.z = fmaf(-p.z, q.z, V.z); V.w = fmaf(-p.w, q.w, V.w);
}

// horizontal 7-tap sliding sums over this lane's 8 cols + 6 halo cols from lane+1
__device__ __forceinline__ void hsum7(const float4 A, const float4 B, int baddr, float o[8]) {
    float n0 = shfl_next(A.x, baddr);
    float n1 = shfl_next(A.y, baddr);
    float n2 = shfl_next(A.z, baddr);
    float n3 = shfl_next(A.w, baddr);
    float n4 = shfl_next(B.x, baddr);
    float n5 = shfl_next(B.y, baddr);
    o[0] = ((A.x + A.y) + (A.z + A.w)) + ((B.x + B.y) + B.z);
    o[1] = (o[0] - A.x) + B.w;
    o[2] = (o[1] - A.y) + n0;
    o[3] = (o[2] - A.z) + n1;
    o[4] = (o[3] - A.w) + n2;
    o[5] = (o[4] - B.x) + n3;
    o[6] = (o[5] - B.y) + n4;
    o[7] = (o[6] - B.z) + n5;
}

#define LOADROW(x0, x1, y0, y1, r) do {                                         \
    const float4* _p = reinterpret_cast<const float4*>(pp + (size_t)(r) * IMG); \
    const float4* _q = reinterpret_cast<const float4*>(pt + (size_t)(r) * IMG); \
    x0 = _p[0]; x1 = _p[1]; y0 = _q[0]; y1 = _q[1]; } while (0)

__global__ __launch_bounds__(256, 4) void ssim_wave_kernel(
    const float* __restrict__ pred,
    const float* __restrict__ target,
    double* __restrict__ accum)
{
    const int t     = threadIdx.x;
    const int lane  = t & 63;
    const int wv    = t >> 6;
    const int band  = blockIdx.x * 4 + wv;      // 0..51 (51 = pad band)
    const int plane = blockIdx.y;
    const int row0  = band * R;
    const int col   = lane << 3;                // this lane's 8 columns

    if (row0 >= VALID) return;                  // pad band: no barriers anywhere, safe

    const size_t pbase = (size_t)plane * (IMG * IMG);
    const float* __restrict__ pp = pred   + pbase + col;
    const float* __restrict__ pt = target + pbase + col;

    const int baddr = ((lane + 1) & 63) << 2;   // ds_bpermute addr: lane+1

    float4 z = make_float4(0.f, 0.f, 0.f, 0.f);
    float4 Vx_a = z, Vx_b = z, Vy_a = z, Vy_b = z;
    float4 Vss_a = z, Vss_b = z, Vxy_a = z, Vxy_b = z;   // Vss = Vxx + Vyy merged

    float4 nx0, nx1, ny0, ny1;                  // prefetched incoming row
    LOADROW(nx0, nx1, ny0, ny1, row0);

    // ---- prologue: accumulate input rows row0 .. row0+5 ----
    #pragma unroll
    for (int k = 0; k < 6; ++k) {
        float4 px0 = nx0, px1 = nx1, py0 = ny0, py1 = ny1;
        LOADROW(nx0, nx1, ny0, ny1, row0 + k + 1);    // k=5 -> row0+6 (iter-0 row)
        addv(Vx_a, px0);  addv(Vx_b, px1);
        addv(Vy_a, py0);  addv(Vy_b, py1);
        addmul(Vss_a, px0, px0); addmul(Vss_b, px1, px1);
        addmul(Vss_a, py0, py0); addmul(Vss_b, py1, py1);
        addmul(Vxy_a, px0, py0); addmul(Vxy_b, px1, py1);
    }

    // old-row prefetch for iter 1 (iter 0 has no subtract)
    float4 pox0, pox1, poy0, poy1;
    LOADROW(pox0, pox1, poy0, poy1, row0);

    const float c1 = 0.9604f;   // (0.01*2)^2 * 49^2
    const float c2 = 8.4672f;   // (0.03*2)^2 * 48*49
    float local = 0.f;

    #pragma unroll
    for (int i = 0; i < R; ++i) {
        float4 px0 = nx0, px1 = nx1, py0 = ny0, py1 = ny1;
        float4 ox0 = pox0, ox1 = pox1, oy0 = poy0, oy1 = poy1;

        // prefetch for iter i+1: incoming row row0+7+i (clamped), old row row0+i
        if (i < R - 1) {
            int rn = row0 + 7 + i; rn = rn < IMG - 1 ? rn : IMG - 1;
            LOADROW(nx0, nx1, ny0, ny1, rn);
            if (i > 0) LOADROW(pox0, pox1, poy0, poy1, row0 + i);
        }

        // vertical sliding update
        addv(Vx_a, px0);  addv(Vx_b, px1);
        addv(Vy_a, py0);  addv(Vy_b, py1);
        addmul(Vss_a, px0, px0); addmul(Vss_b, px1, px1);
        addmul(Vss_a, py0, py0); addmul(Vss_b, py1, py1);
        addmul(Vxy_a, px0, py0); addmul(Vxy_b, px1, py1);
        if (i > 0) {
            subv(Vx_a, ox0);  subv(Vx_b, ox1);
            subv(Vy_a, oy0);  subv(Vy_b, oy1);
            submul(Vss_a, ox0, ox0); submul(Vss_b, ox1, ox1);
            submul(Vss_a, oy0, oy0); submul(Vss_b, oy1, oy1);
            submul(Vxy_a, ox0, oy0); submul(Vxy_b, ox1, oy1);
        }

        const bool row_ok = (row0 + i) < VALID;   // wave-uniform
        if (row_ok) {
            float hx[8], hy[8], hss[8], hxy[8];
            hsum7(Vx_a,  Vx_b,  baddr, hx);
            hsum7(Vy_a,  Vy_b,  baddr, hy);
            hsum7(Vss_a, Vss_b, baddr, hss);
            hsum7(Vxy_a, Vxy_b, baddr, hxy);
            #pragma unroll
            for (int j = 0; j < 8; ++j) {
                float t1 = hx[j] * hy[j];
                float t2 = fmaf(hx[j], hx[j], hy[j] * hy[j]);
                float n1 = fmaf(2.f, t1, c1);
                float d1 = t2 + c1;
                float n2 = fmaf(-2.f, t1, fmaf(98.f, hxy[j], c2));
                float d2 = fmaf(49.f, hss[j], c2) - t2;
                float S  = __fdividef(n1 * n2, d1 * d2);
                local += (col + j < VALID) ? S : 0.f;
            }
        }
    }

    // per-wave reduce -> one atomic per wave, scattered per plane (no barriers)
    #pragma unroll
    for (int off = 32; off > 0; off >>= 1)
        local += __shfl_down(local, off, 64);
    if (lane == 0)
        atomicAdd(&accum[plane], (double)local);
}

__global__ void ssim_finalize_kernel(const double* __restrict__ accum,
                                     float* __restrict__ out)
{
    const int l = threadIdx.x;           // 64 threads = 1 wave
    double s = accum[l];
    if (l < NPLANES - 64) s += accum[64 + l];
    #pragma unroll
    for (int off = 32; off > 0; off >>= 1)
        s += __shfl_down(s, off, 64);
    if (l == 0) {
        const double n_valid = (double)NPLANES * (double)VALID * (double)VALID;
        out[0] = (float)(1.0 - s / n_valid);
    }
}

extern "C" void kernel_launch(void* const* d_in, const int* in_sizes, int n_in,
                              void* d_out, int out_size, void* d_ws, size_t ws_size,
                              hipStream_t stream) {
    const float* pred   = (const float*)d_in[0];
    const float* target = (const float*)d_in[1];
    float* out = (float*)d_out;
    double* accum = (double*)d_ws;

    hipMemsetAsync(d_ws, 0, NPLANES * sizeof(double), stream);

    // 13 x 96 = 1248 blocks (4 wave-bands each, band 51 = pad) -> 4.9 blocks/CU:
    // one residency generation at 5 blocks/CU (VGPR<=102), no second-gen tail.
    dim3 grid((NBANDS + 4) / 4, NPLANES);
    ssim_wave_kernel<<<grid, 256, 0, stream>>>(pred, target, accum);
    ssim_finalize_kernel<<<1, 64, 0, stream>>>(accum, out);
}

// Round 9
// 91.321 us; speedup vs baseline: 5.5925x; 2.4589x over previous
//
#include <hip/hip_runtime.h>

#define IMG     512
#define VALID   506          // IMG - 6
#define NPLANES 96           // 32 * 3
#define R       8            // output rows per wave-band
#define NBANDS  64           // 64 * 8 = 512 >= 506

struct Q { float4 x0, x1, y0, y1; };

__device__ __forceinline__ float shfl_next(float v, int baddr) {
    return __int_as_float(__builtin_amdgcn_ds_bpermute(baddr, __float_as_int(v)));
}

__device__ __forceinline__ void addv(float4& V, const float4 p) {
    V.x += p.x; V.y += p.y; V.z += p.z; V.w += p.w;
}
__device__ __forceinline__ void subv(float4& V, const float4 p) {
    V.x -= p.x; V.y -= p.y; V.z -= p.z; V.w -= p.w;
}
__device__ __forceinline__ void addmul(float4& V, const float4 p, const float4 q) {
    V.x = fmaf(p.x, q.x, V.x); V.y = fmaf(p.y, q.y, V.y);
    V.z = fmaf(p.z, q.z, V.z); V.w = fmaf(p.w, q.w, V.w);
}
__device__ __forceinline__ void submul(float4& V, const float4 p, const float4 q) {
    V.x = fmaf(-p.x, q.x, V.x); V.y = fmaf(-p.y, q.y, V.y);
    V.z = fmaf(-p.z, q.z, V.z); V.w = fmaf(-p.w, q.w, V.w);
}

// horizontal 7-tap sliding sums over this lane's 8 cols + 6 halo cols from lane+1
__device__ __forceinline__ void hsum7(const float4 A, const float4 B, int baddr, float o[8]) {
    float n0 = shfl_next(A.x, baddr);
    float n1 = shfl_next(A.y, baddr);
    float n2 = shfl_next(A.z, baddr);
    float n3 = shfl_next(A.w, baddr);
    float n4 = shfl_next(B.x, baddr);
    float n5 = shfl_next(B.y, baddr);
    o[0] = ((A.x + A.y) + (A.z + A.w)) + ((B.x + B.y) + B.z);
    o[1] = (o[0] - A.x) + B.w;
    o[2] = (o[1] - A.y) + n0;
    o[3] = (o[2] - A.z) + n1;
    o[4] = (o[3] - A.w) + n2;
    o[5] = (o[4] - B.x) + n3;
    o[6] = (o[5] - B.y) + n4;
    o[7] = (o[6] - B.z) + n5;
}

// NOTE: plain __launch_bounds__(256). (256,4) empirically pins VGPR=64 on this
// compiler (R5/R8: 257-333 MB scratch spill). Do not add a min-waves arg.
__global__ __launch_bounds__(256) void ssim_wave_kernel(
    const float* __restrict__ pred,
    const float* __restrict__ target,
    double* __restrict__ accum)
{
    const int t     = threadIdx.x;
    const int lane  = t & 63;
    const int wv    = t >> 6;
    const int band  = blockIdx.x * 4 + wv;      // 0..63, all active
    const int plane = blockIdx.y;
    const int row0  = band * R;
    const int col   = lane << 3;                // this lane's 8 columns

    const size_t pbase = (size_t)plane * (IMG * IMG);
    const float* __restrict__ pp = pred   + pbase + col;
    const float* __restrict__ pt = target + pbase + col;

    const int baddr = ((lane + 1) & 63) << 2;   // ds_bpermute addr: lane+1

    float4 z = make_float4(0.f, 0.f, 0.f, 0.f);
    float4 Vx_a = z, Vx_b = z, Vy_a = z, Vy_b = z;
    float4 Vss_a = z, Vss_b = z, Vxy_a = z, Vxy_b = z;   // Vss = Vxx + Vyy merged

#define LOADQ(q, r) do { int _rr = (r) < (IMG - 1) ? (r) : (IMG - 1);             \
    const float4* _p  = reinterpret_cast<const float4*>(pp + (size_t)_rr * IMG); \
    const float4* _q2 = reinterpret_cast<const float4*>(pt + (size_t)_rr * IMG); \
    q.x0 = _p[0]; q.x1 = _p[1]; q.y0 = _q2[0]; q.y1 = _q2[1]; } while (0)

#define ACCQ(q) do {                                                        \
    addv(Vx_a, q.x0); addv(Vx_b, q.x1); addv(Vy_a, q.y0); addv(Vy_b, q.y1); \
    addmul(Vss_a, q.x0, q.x0); addmul(Vss_b, q.x1, q.x1);                   \
    addmul(Vss_a, q.y0, q.y0); addmul(Vss_b, q.y1, q.y1);                   \
    addmul(Vxy_a, q.x0, q.y0); addmul(Vxy_b, q.x1, q.y1); } while (0)

#define SUBQ(q) do {                                                        \
    subv(Vx_a, q.x0); subv(Vx_b, q.x1); subv(Vy_a, q.y0); subv(Vy_b, q.y1); \
    submul(Vss_a, q.x0, q.x0); submul(Vss_b, q.x1, q.x1);                   \
    submul(Vss_a, q.y0, q.y0); submul(Vss_b, q.y1, q.y1);                   \
    submul(Vxy_a, q.x0, q.y0); submul(Vxy_b, q.x1, q.y1); } while (0)

    const float c1 = 0.9604f;   // (0.01*2)^2 * 49^2
    const float c2 = 8.4672f;   // (0.03*2)^2 * 48*49
    float local = 0.f;

#define HSSIM(i) do { if ((row0 + (i)) < VALID) {                      \
    float hx[8], hy[8], hss[8], hxy[8];                                \
    hsum7(Vx_a,  Vx_b,  baddr, hx);                                    \
    hsum7(Vy_a,  Vy_b,  baddr, hy);                                    \
    hsum7(Vss_a, Vss_b, baddr, hss);                                   \
    hsum7(Vxy_a, Vxy_b, baddr, hxy);                                   \
    _Pragma("unroll")                                                  \
    for (int j = 0; j < 8; ++j) {                                      \
        float t1 = hx[j] * hy[j];                                      \
        float t2 = fmaf(hx[j], hx[j], hy[j] * hy[j]);                  \
        float n1 = fmaf(2.f, t1, c1);                                  \
        float d1 = t2 + c1;                                            \
        float n2 = fmaf(-2.f, t1, fmaf(98.f, hxy[j], c2));             \
        float d2 = fmaf(49.f, hss[j], c2) - t2;                        \
        float S  = __fdividef(n1 * n2, d1 * d2);                       \
        local += (col + (j) < VALID) ? S : 0.f;                        \
    } } } while (0)

    // ---- 3 slots: NA/NB new-row ping-pong (issue->consume distance 2 iters),
    //      OL old-row (distance 1, L2-hot). Consume-then-reissue in place:
    //      compiler waits become counted vmcnt(8)/vmcnt(4), never a full drain.
    Q NA, NB, OL;

    // ---- prologue: rows r0..r0+5 accumulated; 3 batches (12 loads) in flight
    LOADQ(NA, row0 + 0); LOADQ(NB, row0 + 1); LOADQ(OL, row0 + 2);
    ACCQ(NA); LOADQ(NA, row0 + 3);
    ACCQ(NB); LOADQ(NB, row0 + 4);
    ACCQ(OL); LOADQ(OL, row0 + 5);
    ACCQ(NA); LOADQ(NA, row0 + 6);   // iter-0 new row
    ACCQ(NB); LOADQ(NB, row0 + 7);   // iter-1 new row
    ACCQ(OL); LOADQ(OL, row0 + 0);   // iter-1 old row (reload, L2-hot)

    // ---- main: iter i consumes new row r0+6+i, subtracts r0+i-1 ----
    // iter 0
    ACCQ(NA);                               LOADQ(NA, row0 + 8);  HSSIM(0);
    // iter 1
    ACCQ(NB); SUBQ(OL); LOADQ(OL, row0+1);  LOADQ(NB, row0 + 9);  HSSIM(1);
    // iter 2
    ACCQ(NA); SUBQ(OL); LOADQ(OL, row0+2);  LOADQ(NA, row0 + 10); HSSIM(2);
    // iter 3
    ACCQ(NB); SUBQ(OL); LOADQ(OL, row0+3);  LOADQ(NB, row0 + 11); HSSIM(3);
    // iter 4
    ACCQ(NA); SUBQ(OL); LOADQ(OL, row0+4);  LOADQ(NA, row0 + 12); HSSIM(4);
    // iter 5
    ACCQ(NB); SUBQ(OL); LOADQ(OL, row0+5);  LOADQ(NB, row0 + 13); HSSIM(5);
    // iter 6
    ACCQ(NA); SUBQ(OL); LOADQ(OL, row0+6);                        HSSIM(6);
    // iter 7
    ACCQ(NB); SUBQ(OL);                                           HSSIM(7);

    // per-wave reduce -> one atomic per wave, scattered per plane (no barriers)
    #pragma unroll
    for (int off = 32; off > 0; off >>= 1)
        local += __shfl_down(local, off, 64);
    if (lane == 0)
        atomicAdd(&accum[plane], (double)local);
}

__global__ void ssim_finalize_kernel(const double* __restrict__ accum,
                                     float* __restrict__ out)
{
    const int l = threadIdx.x;           // 64 threads = 1 wave
    double s = accum[l];
    if (l < NPLANES - 64) s += accum[64 + l];
    #pragma unroll
    for (int off = 32; off > 0; off >>= 1)
        s += __shfl_down(s, off, 64);
    if (l == 0) {
        const double n_valid = (double)NPLANES * (double)VALID * (double)VALID;
        out[0] = (float)(1.0 - s / n_valid);
    }
}

extern "C" void kernel_launch(void* const* d_in, const int* in_sizes, int n_in,
                              void* d_out, int out_size, void* d_ws, size_t ws_size,
                              hipStream_t stream) {
    const float* pred   = (const float*)d_in[0];
    const float* target = (const float*)d_in[1];
    float* out = (float*)d_out;
    double* accum = (double*)d_ws;

    hipMemsetAsync(d_ws, 0, NPLANES * sizeof(double), stream);

    dim3 grid(NBANDS / 4, NPLANES);   // 16 x 96 = 1536 blocks, 4 wave-bands each
    ssim_wave_kernel<<<grid, 256, 0, stream>>>(pred, target, accum);
    ssim_finalize_kernel<<<1, 64, 0, stream>>>(accum, out);
}

// Round 10
// 81.063 us; speedup vs baseline: 6.3003x; 1.1266x over previous
//
#include <hip/hip_runtime.h>

#define IMG     512
#define VALID   506          // IMG - 6
#define NPLANES 96           // 32 * 3
#define R       10           // output rows per wave-band
#define NBANDS  51           // 51*10 = 510 >= 506 (band 51 of 52 grid-slots = pad)

__device__ __forceinline__ float shfl_next(float v, int baddr) {
    return __int_as_float(__builtin_amdgcn_ds_bpermute(baddr, __float_as_int(v)));
}

__device__ __forceinline__ void addv(float4& V, const float4 p) {
    V.x += p.x; V.y += p.y; V.z += p.z; V.w += p.w;
}
__device__ __forceinline__ void subv(float4& V, const float4 p) {
    V.x -= p.x; V.y -= p.y; V.z -= p.z; V.w -= p.w;
}
__device__ __forceinline__ void addmul(float4& V, const float4 p, const float4 q) {
    V.x = fmaf(p.x, q.x, V.x); V.y = fmaf(p.y, q.y, V.y);
    V.z = fmaf(p.z, q.z, V.z); V.w = fmaf(p.w, q.w, V.w);
}
__device__ __forceinline__ void submul(float4& V, const float4 p, const float4 q) {
    V.x = fmaf(-p.x, q.x, V.x); V.y = fmaf(-p.y, q.y, V.y);
    V.z = fmaf(-p.z, q.z, V.z); V.w = fmaf(-p.w, q.w, V.w);
}

// horizontal 7-tap sliding sums over this lane's 8 cols + 6 halo cols from lane+1
__device__ __forceinline__ void hsum7(const float4 A, const float4 B, int baddr, float o[8]) {
    float n0 = shfl_next(A.x, baddr);
    float n1 = shfl_next(A.y, baddr);
    float n2 = shfl_next(A.z, baddr);
    float n3 = shfl_next(A.w, baddr);
    float n4 = shfl_next(B.x, baddr);
    float n5 = shfl_next(B.y, baddr);
    o[0] = ((A.x + A.y) + (A.z + A.w)) + ((B.x + B.y) + B.z);
    o[1] = (o[0] - A.x) + B.w;
    o[2] = (o[1] - A.y) + n0;
    o[3] = (o[2] - A.z) + n1;
    o[4] = (o[3] - A.w) + n2;
    o[5] = (o[4] - B.x) + n3;
    o[6] = (o[5] - B.y) + n4;
    o[7] = (o[6] - B.z) + n5;
}

#define LOADROW(x0, x1, y0, y1, r) do {                                         \
    const float4* _p = reinterpret_cast<const float4*>(pp + (size_t)(r) * IMG); \
    const float4* _q = reinterpret_cast<const float4*>(pt + (size_t)(r) * IMG); \
    x0 = _p[0]; x1 = _p[1]; y0 = _q[0]; y1 = _q[1]; } while (0)

// NOTE: plain __launch_bounds__(256). (256,4) empirically pins VGPR=64 on this
// compiler (R5/R8: 257-333 MB scratch spill). Do not add a min-waves arg.
__global__ __launch_bounds__(256) void ssim_wave_kernel(
    const float* __restrict__ pred,
    const float* __restrict__ target,
    double* __restrict__ accum)
{
    const int t     = threadIdx.x;
    const int lane  = t & 63;
    const int wv    = t >> 6;
    const int band  = blockIdx.x * 4 + wv;      // 0..51 (51 = pad band)
    const int plane = blockIdx.y;
    const int row0  = band * R;
    const int col   = lane << 3;                // this lane's 8 columns

    if (row0 >= VALID) return;                  // pad band: kernel is barrier-free

    const size_t pbase = (size_t)plane * (IMG * IMG);
    const float* __restrict__ pp = pred   + pbase + col;
    const float* __restrict__ pt = target + pbase + col;

    const int baddr = ((lane + 1) & 63) << 2;   // ds_bpermute addr: lane+1

    float4 z = make_float4(0.f, 0.f, 0.f, 0.f);
    float4 Vx_a = z, Vx_b = z, Vy_a = z, Vy_b = z;
    float4 Vss_a = z, Vss_b = z, Vxy_a = z, Vxy_b = z;   // Vss = Vxx + Vyy merged

    float4 nx0, nx1, ny0, ny1;                  // prefetched incoming row
    LOADROW(nx0, nx1, ny0, ny1, row0);

    // ---- prologue: accumulate input rows row0 .. row0+5 ----
    #pragma unroll
    for (int k = 0; k < 6; ++k) {
        float4 px0 = nx0, px1 = nx1, py0 = ny0, py1 = ny1;
        LOADROW(nx0, nx1, ny0, ny1, row0 + k + 1);    // k=5 -> row0+6 (iter-0 row)
        addv(Vx_a, px0);  addv(Vx_b, px1);
        addv(Vy_a, py0);  addv(Vy_b, py1);
        addmul(Vss_a, px0, px0); addmul(Vss_b, px1, px1);
        addmul(Vss_a, py0, py0); addmul(Vss_b, py1, py1);
        addmul(Vxy_a, px0, py0); addmul(Vxy_b, px1, py1);
    }

    // old-row prefetch for iter 1 (iter 0 has no subtract)
    float4 pox0, pox1, poy0, poy1;
    LOADROW(pox0, pox1, poy0, poy1, row0);

    const float c1 = 0.9604f;   // (0.01*2)^2 * 49^2
    const float c2 = 8.4672f;   // (0.03*2)^2 * 48*49
    float local = 0.f;

    #pragma unroll
    for (int i = 0; i < R; ++i) {
        float4 px0 = nx0, px1 = nx1, py0 = ny0, py1 = ny1;
        float4 ox0 = pox0, ox1 = pox1, oy0 = poy0, oy1 = poy1;

        // prefetch for iter i+1: incoming row row0+7+i (clamped), old row row0+i
        if (i < R - 1) {
            int rn = row0 + 7 + i; rn = rn < IMG - 1 ? rn : IMG - 1;
            LOADROW(nx0, nx1, ny0, ny1, rn);
            if (i > 0) LOADROW(pox0, pox1, poy0, poy1, row0 + i);
        }

        // vertical sliding update
        addv(Vx_a, px0);  addv(Vx_b, px1);
        addv(Vy_a, py0);  addv(Vy_b, py1);
        addmul(Vss_a, px0, px0); addmul(Vss_b, px1, px1);
        addmul(Vss_a, py0, py0); addmul(Vss_b, py1, py1);
        addmul(Vxy_a, px0, py0); addmul(Vxy_b, px1, py1);
        if (i > 0) {
            subv(Vx_a, ox0);  subv(Vx_b, ox1);
            subv(Vy_a, oy0);  subv(Vy_b, oy1);
            submul(Vss_a, ox0, ox0); submul(Vss_b, ox1, ox1);
            submul(Vss_a, oy0, oy0); submul(Vss_b, oy1, oy1);
            submul(Vxy_a, ox0, oy0); submul(Vxy_b, ox1, oy1);
        }

        const bool row_ok = (row0 + i) < VALID;   // wave-uniform
        if (row_ok) {
            float hx[8], hy[8], hss[8], hxy[8];
            hsum7(Vx_a,  Vx_b,  baddr, hx);
            hsum7(Vy_a,  Vy_b,  baddr, hy);
            hsum7(Vss_a, Vss_b, baddr, hss);
            hsum7(Vxy_a, Vxy_b, baddr, hxy);
            #pragma unroll
            for (int j = 0; j < 8; ++j) {
                float t1 = hx[j] * hy[j];
                float t2 = fmaf(hx[j], hx[j], hy[j] * hy[j]);
                float n1 = fmaf(2.f, t1, c1);
                float d1 = t2 + c1;
                float n2 = fmaf(-2.f, t1, fmaf(98.f, hxy[j], c2));
                float d2 = fmaf(49.f, hss[j], c2) - t2;
                float S  = __fdividef(n1 * n2, d1 * d2);
                local += (col + j < VALID) ? S : 0.f;
            }
        }
    }

    // per-wave reduce -> one atomic per wave, scattered per plane (no barriers)
    #pragma unroll
    for (int off = 32; off > 0; off >>= 1)
        local += __shfl_down(local, off, 64);
    if (lane == 0)
        atomicAdd(&accum[plane], (double)local);
}

__global__ void ssim_finalize_kernel(const double* __restrict__ accum,
                                     float* __restrict__ out)
{
    const int l = threadIdx.x;           // 64 threads = 1 wave
    double s = accum[l];
    if (l < NPLANES - 64) s += accum[64 + l];
    #pragma unroll
    for (int off = 32; off > 0; off >>= 1)
        s += __shfl_down(s, off, 64);
    if (l == 0) {
        const double n_valid = (double)NPLANES * (double)VALID * (double)VALID;
        out[0] = (float)(1.0 - s / n_valid);
    }
}

extern "C" void kernel_launch(void* const* d_in, const int* in_sizes, int n_in,
                              void* d_out, int out_size, void* d_ws, size_t ws_size,
                              hipStream_t stream) {
    const float* pred   = (const float*)d_in[0];
    const float* target = (const float*)d_in[1];
    float* out = (float*)d_out;
    double* accum = (double*)d_ws;

    hipMemsetAsync(d_ws, 0, NPLANES * sizeof(double), stream);

    // 13 x 96 = 1248 blocks (4 wave-bands each, band 51 = pad).
    // At VGPR ~88 -> 5 blocks/CU -> 1280 slots: single residency generation.
    dim3 grid((NBANDS + 4) / 4, NPLANES);
    ssim_wave_kernel<<<grid, 256, 0, stream>>>(pred, target, accum);
    ssim_finalize_kernel<<<1, 64, 0, stream>>>(accum, out);
}